// Round 13
// baseline (270.755 us; speedup 1.0000x reference)
//
#include <hip/hip_runtime.h>
#include <stdint.h>

typedef _Float16 f16;
typedef f16 f16x8 __attribute__((ext_vector_type(8)));
typedef float f32x4 __attribute__((ext_vector_type(4)));

#define NUM_NODES 20000
#define NUM_EDGES 65536
#define WIDTH 64
#define EDGE_FEAT 6
#define HIDDEN 128
#define BM 128            // edges per workgroup (grid 512 = 2 blocks/CU exact)
#define NCHUNK 129        // 128 h-chunks + 1 bias chunk
#define XPAD 72           // x-tile row stride in halfs
#define HPAD 130          // hbuf row stride in halfs
#define GRID_BLKS (NUM_EDGES / BM)     // 512

#define W2G_HALFS (NCHUNK * 4096)      // 528,384 halfs
#define OUT_FLOATS (NUM_NODES * WIDTH) // 1,280,000

// direct global->LDS DMA, 16B per lane. lds dest wave-uniform; HW adds lane*16.
__device__ __forceinline__ void gload_lds16(const f16* g, f16* l) {
  __builtin_amdgcn_global_load_lds(
      (const __attribute__((address_space(1))) unsigned int*)g,
      (__attribute__((address_space(3))) unsigned int*)l, 16, 0, 0);
}

// ---------------------------------------------------------------------------
// ONE fused kernel. Grid 512 x 256 thr = exactly 2 blocks/CU (LDS 76.3 KB,
// VGPR ~90 -> guaranteed co-residency; device spin-barrier is safe).
//  P1: blocks 0..128  -> W2g chunk transform (f16, transposed, XOR-swizzled;
//                        chunk 128 = bias b2). 16 KB LDS staging in hbuf.
//      blocks 129..511-> zero `out`.
//  BARRIER: ws counter (re-zeroed per replay by captured hipMemsetAsync),
//      device-scope atomics + threadfences, tid0 spins, syncthreads fan-out.
//  P2: r9 nnconv body: hbuf h-precompute, x gathered fp32->f16 in-register
//      (x_h prep deleted), 3-slot ring, 6x-unrolled counted loop, setprio,
//      atomicAdd scatter epilogue.
// ---------------------------------------------------------------------------
__global__ __launch_bounds__(256, 2) void fused_kernel(
    const float* __restrict__ x, const float* __restrict__ ea,
    const float* __restrict__ W1, const float* __restrict__ b1,
    const float* __restrict__ W2, const float* __restrict__ b2,
    const int* __restrict__ senders, const int* __restrict__ receivers,
    f16* __restrict__ ws_h, float* __restrict__ out)
{
  f16* W2g = ws_h;
  unsigned int* ctr = (unsigned int*)(ws_h + W2G_HALFS);

  __shared__ __align__(16) f16 xt[BM][XPAD];       // 18,432 B
  __shared__ __align__(16) f16 hbuf[HIDDEN * HPAD];// 33,280 B
  __shared__ __align__(16) f16 ring[3 * 4096];     // 24,576 B (76,288 total)

  const int tid = threadIdx.x;
  const int blk = blockIdx.x;

  // ======================= P1: distributed prep ===========================
  if (blk < NCHUNK) {
    // ---- W2 chunk transform (staging buffer aliased onto hbuf: 16 KB) ----
    float* row = (float*)&hbuf[0];
    const int ki = blk;
    const float* srcrow;
    if (ki < HIDDEN) {
      const float4* src = (const float4*)(W2 + (size_t)ki * 4096);
      #pragma unroll
      for (int i = 0; i < 4; ++i) {
        float4 v = src[tid + 256 * i];
        *(float4*)&row[(tid + 256 * i) * 4] = v;
      }
      __syncthreads();
      srcrow = row;
    } else {
      srcrow = b2;  // bias chunk
    }
    const int obase = tid * 16;
    f16x8 outv0, outv1;
    #pragma unroll
    for (int u = 0; u < 8; ++u) {
      int o = obase + u;
      int n = o >> 6, pg = (o >> 3) & 7, j = o & 7;
      int k = (pg ^ (n & 7)) * 8 + j;
      outv0[u] = (f16)srcrow[k * 64 + n];
    }
    #pragma unroll
    for (int u = 0; u < 8; ++u) {
      int o = obase + 8 + u;
      int n = o >> 6, pg = (o >> 3) & 7, j = o & 7;
      int k = (pg ^ (n & 7)) * 8 + j;
      outv1[u] = (f16)srcrow[k * 64 + n];
    }
    *(f16x8*)&W2g[(size_t)ki * 4096 + obase] = outv0;
    *(f16x8*)&W2g[(size_t)ki * 4096 + obase + 8] = outv1;
    __syncthreads();  // hbuf (row alias) free before P2 reuses it
  } else {
    // ---- zero `out`: 313 slices of 4096 floats over blocks 129..511 ----
    for (int i = blk - NCHUNK; i < 313; i += GRID_BLKS - NCHUNK) {
      int base = i * 4096 + tid * 16;
      float4 z = {0.f, 0.f, 0.f, 0.f};
      #pragma unroll
      for (int u = 0; u < 4; ++u) {
        int idx = base + u * 4;
        if (idx + 4 <= OUT_FLOATS) *(float4*)(out + idx) = z;
      }
    }
  }

  // ======================= device-wide barrier ============================
  __threadfence();   // all P1 global writes visible device-wide
  __syncthreads();
  if (tid == 0) {
    __hip_atomic_fetch_add(ctr, 1u, __ATOMIC_ACQ_REL, __HIP_MEMORY_SCOPE_AGENT);
    while (__hip_atomic_load(ctr, __ATOMIC_ACQUIRE, __HIP_MEMORY_SCOPE_AGENT)
           < (unsigned)GRID_BLKS) {
      __builtin_amdgcn_s_sleep(8);
    }
  }
  __syncthreads();
  __threadfence();
  __builtin_amdgcn_sched_barrier(0);

  // ======================= P2: nnconv (r9 body) ===========================
  const int lane = tid & 63, wid = tid >> 6;
  const int quad = lane >> 4, l15 = lane & 15;
  const int mhalf = wid >> 1, nhalf = wid & 1;
  const int e0 = blk * BM;
  const int mbase = mhalf * 64;

  // per-wave DMA slice: 1024 halfs of each 4096-half chunk
  const f16* wsrc = W2g + wid * 1024 + (lane << 3);
  const int stg_off = wid * 1024;          // wave-uniform LDS offset (halfs)

  // ---- prologue stage: chunks 0,1 -> slots 0,1  (4 DMA)
  gload_lds16(wsrc, &ring[stg_off]);
  gload_lds16(wsrc + 512, &ring[stg_off + 512]);
  gload_lds16(wsrc + 4096, &ring[4096 + stg_off]);
  gload_lds16(wsrc + 4096 + 512, &ring[4096 + stg_off + 512]);

  // ---- ea rows for this block -> LDS (aliases ring slot 2; freed pre-loop)
  float* eaf = (float*)&ring[2 * 4096];    // 768 f32 = 3072 B
  if (tid < 192)
    ((float4*)eaf)[tid] = ((const float4*)(ea + (size_t)e0 * EDGE_FEAT))[tid];

  // ---- gather sender x rows fp32 -> f16 in-register: 2 thr/row, 32 floats
  {
    int r = tid >> 1, half = tid & 1;
    int s = senders[e0 + r];
    const float4* src = (const float4*)(x + (size_t)s * WIDTH + half * 32);
    f16* dst = &xt[r][half * 32];
    #pragma unroll
    for (int i = 0; i < 4; ++i) {
      float4 a = src[2 * i];
      float4 b = src[2 * i + 1];
      f16x8 hv;
      hv[0] = (f16)a.x; hv[1] = (f16)a.y; hv[2] = (f16)a.z; hv[3] = (f16)a.w;
      hv[4] = (f16)b.x; hv[5] = (f16)b.y; hv[6] = (f16)b.z; hv[7] = (f16)b.w;
      *(f16x8*)&dst[i * 8] = hv;
    }
  }

  __syncthreads();  // eaf + xt ready (also drains prologue stages)

  // ---- h precompute: thread (k = tid>>1, half) does 64 edges of row k
  {
    const int k = tid >> 1, half = tid & 1;
    float b1c = b1[k];
    float w1c[6];
    #pragma unroll
    for (int f = 0; f < 6; ++f) w1c[f] = W1[f * HIDDEN + k];
    f16* hrow = &hbuf[k * HPAD + half * 64];
    const float* er = eaf + half * 64 * EDGE_FEAT;
    #pragma unroll 2
    for (int g8 = 0; g8 < 8; ++g8) {
      f16x8 hv;
      #pragma unroll
      for (int j = 0; j < 8; ++j) {
        const float* p = er + (g8 * 8 + j) * EDGE_FEAT;
        float s = b1c;
        #pragma unroll
        for (int f = 0; f < 6; ++f) s = fmaf(p[f], w1c[f], s);
        hv[j] = (f16)fmaxf(s, 0.f);
      }
      *(f16x8*)&hrow[g8 * 8] = hv;
    }
  }

  // ---- x fragments (A: m=l15, k-octet=quad), held in regs all loop
  f16x8 xf[4][2];
  #pragma unroll
  for (int t = 0; t < 4; ++t)
    #pragma unroll
    for (int kc = 0; kc < 2; ++kc)
      xf[t][kc] = *(const f16x8*)&xt[mbase + t * 16 + l15][kc * 32 + quad * 8];

  // ---- per-lane B-fragment offsets within a chunk (swizzled), in halfs
  int boff[2][2];
  #pragma unroll
  for (int kc = 0; kc < 2; ++kc)
    #pragma unroll
    for (int nt = 0; nt < 2; ++nt) {
      int n = nhalf * 32 + nt * 16 + l15;
      int g = kc * 4 + quad;
      boff[kc][nt] = n * 64 + (g ^ (n & 7)) * 8;
    }

  const f16* hb = &hbuf[mbase + l15];      // hb[k*HPAD + t*16]

  f32x4 acc[4][2];
  #pragma unroll
  for (int t = 0; t < 4; ++t)
    #pragma unroll
    for (int nt = 0; nt < 2; ++nt)
      acc[t][nt] = (f32x4){0.f, 0.f, 0.f, 0.f};

  __syncthreads();  // hbuf ready; eaf dead -> slot 2 reusable

#define STEP(K, SLOT, STG, SDST, VM)                                          \
  {                                                                           \
    asm volatile("s_waitcnt vmcnt(%0) lgkmcnt(0)\n\ts_barrier"                \
                 :: "i"(VM) : "memory");                                      \
    __builtin_amdgcn_sched_barrier(0);                                        \
    if (STG) {                                                                \
      const f16* s_ = wsrc + (size_t)((K) + 2) * 4096;                        \
      f16* d_ = &ring[(SDST) * 4096 + stg_off];                               \
      gload_lds16(s_, d_);                                                    \
      gload_lds16(s_ + 512, d_ + 512);                                        \
    }                                                                         \
    __builtin_amdgcn_sched_barrier(0);                                        \
    f16 hv_[4];                                                               \
    _Pragma("unroll") for (int t = 0; t < 4; ++t)                             \
      hv_[t] = hb[(K) * HPAD + t * 16];                                       \
    const f16* gb_ = &ring[(SLOT) * 4096];                                    \
    f16x8 bf_[2][2];                                                          \
    _Pragma("unroll") for (int kc = 0; kc < 2; ++kc)                          \
      _Pragma("unroll") for (int nt = 0; nt < 2; ++nt)                        \
        bf_[kc][nt] = *(const f16x8*)&gb_[boff[kc][nt]];                      \
    f16x8 sa0_[4], sa1_[4];                                                   \
    _Pragma("unroll") for (int t = 0; t < 4; ++t) {                           \
      sa0_[t] = xf[t][0] * hv_[t];                                            \
      sa1_[t] = xf[t][1] * hv_[t];                                            \
    }                                                                         \
    __builtin_amdgcn_s_setprio(1);                                            \
    _Pragma("unroll") for (int t = 0; t < 4; ++t)                             \
      _Pragma("unroll") for (int nt = 0; nt < 2; ++nt)                        \
        acc[t][nt] = __builtin_amdgcn_mfma_f32_16x16x32_f16(                  \
            sa0_[t], bf_[0][nt], acc[t][nt], 0, 0, 0);                        \
    _Pragma("unroll") for (int t = 0; t < 4; ++t)                             \
      _Pragma("unroll") for (int nt = 0; nt < 2; ++nt)                        \
        acc[t][nt] = __builtin_amdgcn_mfma_f32_16x16x32_f16(                  \
            sa1_[t], bf_[1][nt], acc[t][nt], 0, 0, 0);                        \
    __builtin_amdgcn_s_setprio(0);                                            \
  }

  // ---- main loop: chunks 0..125, 6x unrolled (slots static: i%3 / (i+2)%3)
  #pragma unroll 1
  for (int kb = 0; kb < 126; kb += 6) {
    STEP(kb + 0, 0, 1, 2, 2);
    STEP(kb + 1, 1, 1, 0, 2);
    STEP(kb + 2, 2, 1, 1, 2);
    STEP(kb + 3, 0, 1, 2, 2);
    STEP(kb + 4, 1, 1, 0, 2);
    STEP(kb + 5, 2, 1, 1, 2);
  }
  // chunks 126 (stage 128 -> slot 2), 127 (no stage)
  STEP(126, 0, 1, 2, 2);
  STEP(127, 1, 0, 0, 2);

  // ---- tail: chunk 128 (bias row, h == 1) from slot 2
  asm volatile("s_waitcnt vmcnt(0) lgkmcnt(0)\n\ts_barrier" ::: "memory");
  __builtin_amdgcn_sched_barrier(0);
  {
    const f16* gb_ = &ring[2 * 4096];
    f16x8 bf_[2][2];
    #pragma unroll
    for (int kc = 0; kc < 2; ++kc)
      #pragma unroll
      for (int nt = 0; nt < 2; ++nt)
        bf_[kc][nt] = *(const f16x8*)&gb_[boff[kc][nt]];
    __builtin_amdgcn_s_setprio(1);
    #pragma unroll
    for (int t = 0; t < 4; ++t)
      #pragma unroll
      for (int nt = 0; nt < 2; ++nt) {
        acc[t][nt] = __builtin_amdgcn_mfma_f32_16x16x32_f16(
            xf[t][0], bf_[0][nt], acc[t][nt], 0, 0, 0);
        acc[t][nt] = __builtin_amdgcn_mfma_f32_16x16x32_f16(
            xf[t][1], bf_[1][nt], acc[t][nt], 0, 0, 0);
      }
    __builtin_amdgcn_s_setprio(0);
  }
#undef STEP

  // ---- epilogue: C row = quad*4 + reg, col = l15; scatter-add (full sums)
  #pragma unroll
  for (int t = 0; t < 4; ++t) {
    int ebase = e0 + mbase + t * 16 + quad * 4;
    int rc[4];
    #pragma unroll
    for (int r = 0; r < 4; ++r) rc[r] = receivers[ebase + r];
    #pragma unroll
    for (int nt = 0; nt < 2; ++nt) {
      int v = (nhalf * 2 + nt) * 16 + l15;
      #pragma unroll
      for (int r = 0; r < 4; ++r)
        atomicAdd(out + (size_t)rc[r] * WIDTH + v, acc[t][nt][r]);
    }
  }
}

extern "C" void kernel_launch(void* const* d_in, const int* in_sizes, int n_in,
                              void* d_out, int out_size, void* d_ws, size_t ws_size,
                              hipStream_t stream) {
  const float* x  = (const float*)d_in[0];
  const float* ea = (const float*)d_in[1];
  const float* W1 = (const float*)d_in[2];
  const float* b1 = (const float*)d_in[3];
  const float* W2 = (const float*)d_in[4];
  const float* b2 = (const float*)d_in[5];
  const int* snd  = (const int*)d_in[6];
  const int* rcv  = (const int*)d_in[7];
  float* out = (float*)d_out;
  f16* wsh = (f16*)d_ws;

  // re-zero the device-barrier counter every launch/replay (graph-safe)
  hipMemsetAsync(wsh + W2G_HALFS, 0, 4, stream);
  fused_kernel<<<GRID_BLKS, 256, 0, stream>>>(
      x, ea, W1, b1, W2, b2, snd, rcv, wsh, out);
}

// Round 14
// 146.097 us; speedup vs baseline: 1.8533x; 1.8533x over previous
//
#include <hip/hip_runtime.h>
#include <stdint.h>

typedef _Float16 f16;
typedef f16 f16x8 __attribute__((ext_vector_type(8)));
typedef float f32x4 __attribute__((ext_vector_type(4)));

#define NUM_NODES 20000
#define NUM_EDGES 65536
#define WIDTH 64
#define EDGE_FEAT 6
#define HIDDEN 128
#define BM 128            // edges per workgroup (grid 512, 2 async blocks/CU)
#define NCHUNK 129        // 128 h-chunks + 1 bias chunk
#define XPAD 72           // x-tile row stride in halfs
#define HPAD 130          // hbuf row stride in halfs

#define XH_HALFS (NUM_NODES * WIDTH)   // 1,280,000 halfs for x in f16
#define XCONV_BLKS 625                 // 625 * 2048 halfs = 1,280,000 exactly
#define W2G_HALFS (NCHUNK * 4096)      // 528,384 halfs
#define OUT_FLOATS (NUM_NODES * WIDTH) // 1,280,000
#define ZBLKS 313                      // 313 * 4096 >= OUT_FLOATS

// direct global->LDS DMA, 16B per lane. lds dest wave-uniform; HW adds lane*16.
__device__ __forceinline__ void gload_lds16(const f16* g, f16* l) {
  __builtin_amdgcn_global_load_lds(
      (const __attribute__((address_space(1))) unsigned int*)g,
      (__attribute__((address_space(3))) unsigned int*)l, 16, 0, 0);
}

// ---------------------------------------------------------------------------
// Prep: (a) W2g: 129 chunks of [64n x 64k] f16, transposed + XOR-granule
//       swizzled (chunk 128 = bias b2); (b) x fp32->f16; (c) zero `out`.
// ---------------------------------------------------------------------------
__global__ __launch_bounds__(256) void prep_kernel(
    const float* __restrict__ x, const float* __restrict__ W2,
    const float* __restrict__ b2, f16* __restrict__ ws_h,
    float* __restrict__ out)
{
  f16* x_h = ws_h;
  f16* W2g = ws_h + XH_HALFS;
  const int blk = blockIdx.x, tid = threadIdx.x;

  if (blk < NCHUNK) {
    __shared__ float row[4096];
    const int ki = blk;
    const float* srcrow;
    if (ki < HIDDEN) {
      const float4* src = (const float4*)(W2 + (size_t)ki * 4096);
      #pragma unroll
      for (int i = 0; i < 4; ++i) {
        float4 v = src[tid + 256 * i];
        *(float4*)&row[(tid + 256 * i) * 4] = v;
      }
      __syncthreads();
      srcrow = row;
    } else {
      srcrow = b2;  // bias chunk
    }
    const int obase = tid * 16;
    f16x8 outv0, outv1;
    #pragma unroll
    for (int u = 0; u < 8; ++u) {
      int o = obase + u;
      int n = o >> 6, pg = (o >> 3) & 7, j = o & 7;
      int k = (pg ^ (n & 7)) * 8 + j;
      outv0[u] = (f16)srcrow[k * 64 + n];
    }
    #pragma unroll
    for (int u = 0; u < 8; ++u) {
      int o = obase + 8 + u;
      int n = o >> 6, pg = (o >> 3) & 7, j = o & 7;
      int k = (pg ^ (n & 7)) * 8 + j;
      outv1[u] = (f16)srcrow[k * 64 + n];
    }
    *(f16x8*)&W2g[(size_t)ki * 4096 + obase] = outv0;
    *(f16x8*)&W2g[(size_t)ki * 4096 + obase + 8] = outv1;
  } else if (blk < NCHUNK + XCONV_BLKS) {
    int idx = (blk - NCHUNK) * 2048 + tid * 8;
    if (idx + 8 <= XH_HALFS) {
      float4 a = *(const float4*)(x + idx);
      float4 b = *(const float4*)(x + idx + 4);
      f16x8 hv;
      hv[0] = (f16)a.x; hv[1] = (f16)a.y; hv[2] = (f16)a.z; hv[3] = (f16)a.w;
      hv[4] = (f16)b.x; hv[5] = (f16)b.y; hv[6] = (f16)b.z; hv[7] = (f16)b.w;
      *(f16x8*)&x_h[idx] = hv;
    }
  } else {
    int base = (blk - NCHUNK - XCONV_BLKS) * 4096 + tid * 16;
    float4 z = {0.f, 0.f, 0.f, 0.f};
    #pragma unroll
    for (int i = 0; i < 4; ++i) {
      int idx = base + i * 4;
      if (idx + 4 <= OUT_FLOATS) *(float4*)(out + idx) = z;
    }
  }
}

// ---------------------------------------------------------------------------
// Main kernel: grid 512, 256 thr (4 waves), 2 ASYNC blocks/CU, full K.
// Wave (mhalf,nhalf) = 64 edges x 32 cols; 16 MFMA per chunk (nt=2 so each
// scaled A-frag feeds 2 MFMAs -> pk_mul overhead 20% of MFMA time).
// VALU-dieted loop: h precomputed to LDS in prologue (4 ds_read_u16/iter),
// 3-slot ring with 6x-unrolled k-loop (static slots + imm offsets),
// counted vmcnt(2) (chunk k drained, k+1 in flight; 2-iter flight).
// Session best: 77.9 us nnconv / 145.4 us total, MfmaUtil 35%.
// ---------------------------------------------------------------------------
__global__ __launch_bounds__(256, 2) void nnconv_kernel(
    const float* __restrict__ ea, const float* __restrict__ W1,
    const float* __restrict__ b1, const int* __restrict__ senders,
    const int* __restrict__ receivers, const f16* __restrict__ ws_h,
    float* __restrict__ out)
{
  const f16* x_h = ws_h;
  const f16* W2g = ws_h + XH_HALFS;
  __shared__ __align__(16) f16 xt[BM][XPAD];       // 18,432 B
  __shared__ __align__(16) f16 hbuf[HIDDEN * HPAD];// 33,280 B
  __shared__ __align__(16) f16 ring[3 * 4096];     // 24,576 B (76,288 total)

  const int tid = threadIdx.x;
  const int lane = tid & 63, wid = tid >> 6;
  const int quad = lane >> 4, l15 = lane & 15;
  const int mhalf = wid >> 1, nhalf = wid & 1;
  const int e0 = blockIdx.x * BM;
  const int mbase = mhalf * 64;

  // per-wave DMA slice: 1024 halfs of each 4096-half chunk
  const f16* wsrc = W2g + wid * 1024 + (lane << 3);
  const int stg_off = wid * 1024;          // wave-uniform LDS offset (halfs)

  // ---- prologue stage: chunks 0,1 -> slots 0,1  (4 DMA)
  gload_lds16(wsrc, &ring[stg_off]);
  gload_lds16(wsrc + 512, &ring[stg_off + 512]);
  gload_lds16(wsrc + 4096, &ring[4096 + stg_off]);
  gload_lds16(wsrc + 4096 + 512, &ring[4096 + stg_off + 512]);

  // ---- ea rows for this block -> LDS (aliases ring slot 2; freed pre-loop)
  float* eaf = (float*)&ring[2 * 4096];    // 768 f32 = 3072 B
  if (tid < 192)
    ((float4*)eaf)[tid] = ((const float4*)(ea + (size_t)e0 * EDGE_FEAT))[tid];

  // ---- gather sender x rows (f16) into LDS: 2 threads per row, 64B each
  {
    int r = tid >> 1, half = tid & 1;
    int s = senders[e0 + r];
    const uint4* src = (const uint4*)(x_h + (size_t)s * WIDTH + half * 32);
    uint4* dst = (uint4*)&xt[r][half * 32];
    #pragma unroll
    for (int i = 0; i < 4; ++i) dst[i] = src[i];
  }

  __syncthreads();  // eaf + xt ready (also drains prologue stages)

  // ---- h precompute: thread (k = tid>>1, half) does 64 edges of row k
  {
    const int k = tid >> 1, half = tid & 1;
    float b1c = b1[k];
    float w1c[6];
    #pragma unroll
    for (int f = 0; f < 6; ++f) w1c[f] = W1[f * HIDDEN + k];
    f16* hrow = &hbuf[k * HPAD + half * 64];
    const float* er = eaf + half * 64 * EDGE_FEAT;
    #pragma unroll 2
    for (int g8 = 0; g8 < 8; ++g8) {
      f16x8 hv;
      #pragma unroll
      for (int j = 0; j < 8; ++j) {
        const float* p = er + (g8 * 8 + j) * EDGE_FEAT;
        float s = b1c;
        #pragma unroll
        for (int f = 0; f < 6; ++f) s = fmaf(p[f], w1c[f], s);
        hv[j] = (f16)fmaxf(s, 0.f);
      }
      *(f16x8*)&hrow[g8 * 8] = hv;
    }
  }

  // ---- x fragments (A: m=l15, k-octet=quad), held in regs all loop
  f16x8 xf[4][2];
  #pragma unroll
  for (int t = 0; t < 4; ++t)
    #pragma unroll
    for (int kc = 0; kc < 2; ++kc)
      xf[t][kc] = *(const f16x8*)&xt[mbase + t * 16 + l15][kc * 32 + quad * 8];

  // ---- per-lane B-fragment offsets within a chunk (swizzled), in halfs
  int boff[2][2];
  #pragma unroll
  for (int kc = 0; kc < 2; ++kc)
    #pragma unroll
    for (int nt = 0; nt < 2; ++nt) {
      int n = nhalf * 32 + nt * 16 + l15;
      int g = kc * 4 + quad;
      boff[kc][nt] = n * 64 + (g ^ (n & 7)) * 8;
    }

  const f16* hb = &hbuf[mbase + l15];      // hb[k*HPAD + t*16]

  f32x4 acc[4][2];
  #pragma unroll
  for (int t = 0; t < 4; ++t)
    #pragma unroll
    for (int nt = 0; nt < 2; ++nt)
      acc[t][nt] = (f32x4){0.f, 0.f, 0.f, 0.f};

  __syncthreads();  // hbuf ready; eaf dead -> slot 2 reusable

#define STEP(K, SLOT, STG, SDST, VM)                                          \
  {                                                                           \
    asm volatile("s_waitcnt vmcnt(%0) lgkmcnt(0)\n\ts_barrier"                \
                 :: "i"(VM) : "memory");                                      \
    __builtin_amdgcn_sched_barrier(0);                                        \
    if (STG) {                                                                \
      const f16* s_ = wsrc + (size_t)((K) + 2) * 4096;                        \
      f16* d_ = &ring[(SDST) * 4096 + stg_off];                               \
      gload_lds16(s_, d_);                                                    \
      gload_lds16(s_ + 512, d_ + 512);                                        \
    }                                                                         \
    __builtin_amdgcn_sched_barrier(0);                                        \
    f16 hv_[4];                                                               \
    _Pragma("unroll") for (int t = 0; t < 4; ++t)                             \
      hv_[t] = hb[(K) * HPAD + t * 16];                                       \
    const f16* gb_ = &ring[(SLOT) * 4096];                                    \
    f16x8 bf_[2][2];                                                          \
    _Pragma("unroll") for (int kc = 0; kc < 2; ++kc)                          \
      _Pragma("unroll") for (int nt = 0; nt < 2; ++nt)                        \
        bf_[kc][nt] = *(const f16x8*)&gb_[boff[kc][nt]];                      \
    f16x8 sa0_[4], sa1_[4];                                                   \
    _Pragma("unroll") for (int t = 0; t < 4; ++t) {                           \
      sa0_[t] = xf[t][0] * hv_[t];                                            \
      sa1_[t] = xf[t][1] * hv_[t];                                            \
    }                                                                         \
    __builtin_amdgcn_s_setprio(1);                                            \
    _Pragma("unroll") for (int t = 0; t < 4; ++t)                             \
      _Pragma("unroll") for (int nt = 0; nt < 2; ++nt)                        \
        acc[t][nt] = __builtin_amdgcn_mfma_f32_16x16x32_f16(                  \
            sa0_[t], bf_[0][nt], acc[t][nt], 0, 0, 0);                        \
    _Pragma("unroll") for (int t = 0; t < 4; ++t)                             \
      _Pragma("unroll") for (int nt = 0; nt < 2; ++nt)                        \
        acc[t][nt] = __builtin_amdgcn_mfma_f32_16x16x32_f16(                  \
            sa1_[t], bf_[1][nt], acc[t][nt], 0, 0, 0);                        \
    __builtin_amdgcn_s_setprio(0);                                            \
  }

  // ---- main loop: chunks 0..125, 6x unrolled (slots static: i%3 / (i+2)%3)
  #pragma unroll 1
  for (int kb = 0; kb < 126; kb += 6) {
    STEP(kb + 0, 0, 1, 2, 2);
    STEP(kb + 1, 1, 1, 0, 2);
    STEP(kb + 2, 2, 1, 1, 2);
    STEP(kb + 3, 0, 1, 2, 2);
    STEP(kb + 4, 1, 1, 0, 2);
    STEP(kb + 5, 2, 1, 1, 2);
  }
  // chunks 126 (stage 128 -> slot 2), 127 (no stage)
  STEP(126, 0, 1, 2, 2);
  STEP(127, 1, 0, 0, 2);

  // ---- tail: chunk 128 (bias row, h == 1) from slot 2
  asm volatile("s_waitcnt vmcnt(0) lgkmcnt(0)\n\ts_barrier" ::: "memory");
  __builtin_amdgcn_sched_barrier(0);
  {
    const f16* gb_ = &ring[2 * 4096];
    f16x8 bf_[2][2];
    #pragma unroll
    for (int kc = 0; kc < 2; ++kc)
      #pragma unroll
      for (int nt = 0; nt < 2; ++nt)
        bf_[kc][nt] = *(const f16x8*)&gb_[boff[kc][nt]];
    __builtin_amdgcn_s_setprio(1);
    #pragma unroll
    for (int t = 0; t < 4; ++t)
      #pragma unroll
      for (int nt = 0; nt < 2; ++nt) {
        acc[t][nt] = __builtin_amdgcn_mfma_f32_16x16x32_f16(
            xf[t][0], bf_[0][nt], acc[t][nt], 0, 0, 0);
        acc[t][nt] = __builtin_amdgcn_mfma_f32_16x16x32_f16(
            xf[t][1], bf_[1][nt], acc[t][nt], 0, 0, 0);
      }
    __builtin_amdgcn_s_setprio(0);
  }
#undef STEP

  // ---- epilogue: C row = quad*4 + reg, col = l15; scatter-add (full sums)
  #pragma unroll
  for (int t = 0; t < 4; ++t) {
    int ebase = e0 + mbase + t * 16 + quad * 4;
    int rc[4];
    #pragma unroll
    for (int r = 0; r < 4; ++r) rc[r] = receivers[ebase + r];
    #pragma unroll
    for (int nt = 0; nt < 2; ++nt) {
      int v = (nhalf * 2 + nt) * 16 + l15;
      #pragma unroll
      for (int r = 0; r < 4; ++r)
        atomicAdd(out + (size_t)rc[r] * WIDTH + v, acc[t][nt][r]);
    }
  }
}

extern "C" void kernel_launch(void* const* d_in, const int* in_sizes, int n_in,
                              void* d_out, int out_size, void* d_ws, size_t ws_size,
                              hipStream_t stream) {
  const float* x  = (const float*)d_in[0];
  const float* ea = (const float*)d_in[1];
  const float* W1 = (const float*)d_in[2];
  const float* b1 = (const float*)d_in[3];
  const float* W2 = (const float*)d_in[4];
  const float* b2 = (const float*)d_in[5];
  const int* snd  = (const int*)d_in[6];
  const int* rcv  = (const int*)d_in[7];
  float* out = (float*)d_out;
  f16* wsh = (f16*)d_ws;

  const int prep_grid = NCHUNK + XCONV_BLKS + ZBLKS;
  prep_kernel<<<prep_grid, 256, 0, stream>>>(x, W2, b2, wsh, out);
  nnconv_kernel<<<NUM_EDGES / BM, 256, 0, stream>>>(ea, W1, b1, snd, rcv, wsh, out);
}

// Round 15
// 144.012 us; speedup vs baseline: 1.8801x; 1.0145x over previous
//
#include <hip/hip_runtime.h>
#include <stdint.h>

typedef _Float16 f16;
typedef f16 f16x8 __attribute__((ext_vector_type(8)));
typedef float f32x4 __attribute__((ext_vector_type(4)));

#define NUM_NODES 20000
#define NUM_EDGES 65536
#define WIDTH 64
#define EDGE_FEAT 6
#define HIDDEN 128
#define BM 128            // edges per workgroup (grid 512, 2 async blocks/CU)
#define PADCH 132         // 128 h-chunks + bias + 3 zero pads (group prefetch)

#define XH_HALFS (NUM_NODES * WIDTH)   // 1,280,000 halfs for x in f16
#define XCONV_BLKS 625                 // 625 * 2048 halfs = 1,280,000 exactly
#define OUT_FLOATS (NUM_NODES * WIDTH) // 1,280,000
#define ZBLKS 313                      // 313 * 4096 >= OUT_FLOATS

// direct global->LDS DMA, 16B per lane. lds dest wave-uniform; HW adds lane*16.
__device__ __forceinline__ void gload_lds16(const f16* g, f16* l) {
  __builtin_amdgcn_global_load_lds(
      (const __attribute__((address_space(1))) unsigned int*)g,
      (__attribute__((address_space(3))) unsigned int*)l, 16, 0, 0);
}

// ---------------------------------------------------------------------------
// Prep: (a) W2g: 132 chunks of [64n x 64k] f16, transposed + XOR-granule
//       swizzled (chunk 128 = bias b2, 129..131 zeros); (b) x fp32->f16;
//       (c) zero `out`.
// ---------------------------------------------------------------------------
__global__ __launch_bounds__(256) void prep_kernel(
    const float* __restrict__ x, const float* __restrict__ W2,
    const float* __restrict__ b2, f16* __restrict__ ws_h,
    float* __restrict__ out)
{
  f16* x_h = ws_h;
  f16* W2g = ws_h + XH_HALFS;
  const int blk = blockIdx.x, tid = threadIdx.x;

  if (blk < PADCH) {
    const int ki = blk;
    if (ki > HIDDEN) {  // zero pad chunks 129..131
      f16x8 z;
      #pragma unroll
      for (int u = 0; u < 8; ++u) z[u] = (f16)0.f;
      *(f16x8*)&W2g[(size_t)ki * 4096 + tid * 16] = z;
      *(f16x8*)&W2g[(size_t)ki * 4096 + tid * 16 + 8] = z;
      return;
    }
    __shared__ float row[4096];
    const float* srcrow;
    if (ki < HIDDEN) {
      const float4* src = (const float4*)(W2 + (size_t)ki * 4096);
      #pragma unroll
      for (int i = 0; i < 4; ++i) {
        float4 v = src[tid + 256 * i];
        *(float4*)&row[(tid + 256 * i) * 4] = v;
      }
      __syncthreads();
      srcrow = row;
    } else {
      srcrow = b2;  // bias chunk
    }
    const int obase = tid * 16;
    f16x8 outv0, outv1;
    #pragma unroll
    for (int u = 0; u < 8; ++u) {
      int o = obase + u;
      int n = o >> 6, pg = (o >> 3) & 7, j = o & 7;
      int k = (pg ^ (n & 7)) * 8 + j;
      outv0[u] = (f16)srcrow[k * 64 + n];
    }
    #pragma unroll
    for (int u = 0; u < 8; ++u) {
      int o = obase + 8 + u;
      int n = o >> 6, pg = (o >> 3) & 7, j = o & 7;
      int k = (pg ^ (n & 7)) * 8 + j;
      outv1[u] = (f16)srcrow[k * 64 + n];
    }
    *(f16x8*)&W2g[(size_t)ki * 4096 + obase] = outv0;
    *(f16x8*)&W2g[(size_t)ki * 4096 + obase + 8] = outv1;
  } else if (blk < PADCH + XCONV_BLKS) {
    int idx = (blk - PADCH) * 2048 + tid * 8;
    if (idx + 8 <= XH_HALFS) {
      float4 a = *(const float4*)(x + idx);
      float4 b = *(const float4*)(x + idx + 4);
      f16x8 hv;
      hv[0] = (f16)a.x; hv[1] = (f16)a.y; hv[2] = (f16)a.z; hv[3] = (f16)a.w;
      hv[4] = (f16)b.x; hv[5] = (f16)b.y; hv[6] = (f16)b.z; hv[7] = (f16)b.w;
      *(f16x8*)&x_h[idx] = hv;
    }
  } else {
    int base = (blk - PADCH - XCONV_BLKS) * 4096 + tid * 16;
    float4 z = {0.f, 0.f, 0.f, 0.f};
    #pragma unroll
    for (int i = 0; i < 4; ++i) {
      int idx = base + i * 4;
      if (idx + 4 <= OUT_FLOATS) *(float4*)(out + idx) = z;
    }
  }
}

// ---------------------------------------------------------------------------
// Main kernel: grid 512, 256 thr (4 waves), 2 ASYNC blocks/CU, full K.
// Wave (mhalf,nhalf) = 64 edges x 32 cols; 16 MFMA per chunk.
// r15 = r9 with the sync quantum DOUBLED: 2 chunks (one 16 KB group) per
// barrier, 2-group LDS ring. Within a group, chunk c1's ds_reads issue
// under chunk c0's MFMAs (no barrier between -> real overlap; r10's
// cross-barrier hazard doesn't exist inside a group). Barrier/waitcnt
// count halves (64 vs 128). x fragments are gathered DIRECTLY to registers
// (xt eliminated; its LDS was read exactly once), paying for the ring.
// LDS = hbuf 32 KB + ring 32 KB = 64 KB -> 2 blocks/CU guaranteed.
// ---------------------------------------------------------------------------
__global__ __launch_bounds__(256, 2) void nnconv_kernel(
    const float* __restrict__ ea, const float* __restrict__ W1,
    const float* __restrict__ b1, const int* __restrict__ senders,
    const int* __restrict__ receivers, const f16* __restrict__ ws_h,
    float* __restrict__ out)
{
  const f16* x_h = ws_h;
  const f16* W2g = ws_h + XH_HALFS;
  __shared__ __align__(16) f16 hbuf[HIDDEN * 128];  // 32,768 B
  __shared__ __align__(16) f16 ring[2 * 8192];      // 32,768 B (65,536 total)

  const int tid = threadIdx.x;
  const int lane = tid & 63, wid = tid >> 6;
  const int quad = lane >> 4, l15 = lane & 15;
  const int mhalf = wid >> 1, nhalf = wid & 1;
  const int e0 = blockIdx.x * BM;
  const int mbase = mhalf * 64;

  // ---- stage group 0 (chunks 0,1 = 8192 halfs) -> slot 0, FIRST
  const f16* wsl = W2g + wid * 2048 + (lane << 3);  // wave's group slice
  #pragma unroll
  for (int i = 0; i < 4; ++i)
    gload_lds16(wsl + i * 512, &ring[wid * 2048 + i * 512]);

  // ---- ea rows -> eaf (aliases ring slot 1; dead before group 1 staged)
  float* eaf = (float*)&ring[8192];    // 768 f32 = 3072 B
  if (tid < 192)
    ((float4*)eaf)[tid] = ((const float4*)(ea + (size_t)e0 * EDGE_FEAT))[tid];

  // ---- x fragments gathered DIRECTLY into registers (one-time)
  f16x8 xf[4][2];
  {
    int srows[4];
    #pragma unroll
    for (int t = 0; t < 4; ++t)
      srows[t] = senders[e0 + mbase + t * 16 + l15];
    #pragma unroll
    for (int t = 0; t < 4; ++t)
      #pragma unroll
      for (int kc = 0; kc < 2; ++kc)
        xf[t][kc] = *(const f16x8*)(x_h + (size_t)srows[t] * WIDTH +
                                    kc * 32 + quad * 8);
  }

  __syncthreads();  // eaf visible to all

  // ---- h precompute: thread (k = tid>>1, half) does 64 edges of row k
  {
    const int k = tid >> 1, half = tid & 1;
    float b1c = b1[k];
    float w1c[6];
    #pragma unroll
    for (int f = 0; f < 6; ++f) w1c[f] = W1[f * HIDDEN + k];
    f16* hrow = &hbuf[k * 128 + half * 64];
    const float* er = eaf + half * 64 * EDGE_FEAT;
    #pragma unroll 2
    for (int g8 = 0; g8 < 8; ++g8) {
      f16x8 hv;
      #pragma unroll
      for (int j = 0; j < 8; ++j) {
        const float* p = er + (g8 * 8 + j) * EDGE_FEAT;
        float s = b1c;
        #pragma unroll
        for (int f = 0; f < 6; ++f) s = fmaf(p[f], w1c[f], s);
        hv[j] = (f16)fmaxf(s, 0.f);
      }
      *(f16x8*)&hrow[g8 * 8] = hv;
    }
  }

  // ---- per-lane B-fragment offsets within a 4096-half chunk (swizzled)
  int boff[2][2];
  #pragma unroll
  for (int kc = 0; kc < 2; ++kc)
    #pragma unroll
    for (int nt = 0; nt < 2; ++nt) {
      int n = nhalf * 32 + nt * 16 + l15;
      int g = kc * 4 + quad;
      boff[kc][nt] = n * 64 + (g ^ (n & 7)) * 8;
    }

  const f16* hb = &hbuf[mbase + l15];  // hv[t] = hb[k*128 + t*16]

  f32x4 acc[4][2];
  #pragma unroll
  for (int t = 0; t < 4; ++t)
    #pragma unroll
    for (int nt = 0; nt < 2; ++nt)
      acc[t][nt] = (f32x4){0.f, 0.f, 0.f, 0.f};

  __syncthreads();  // hbuf ready; eaf dead -> slot 1 reusable

  // one chunk's worth of compute from an LDS chunk base CB with h row HK
#define CHUNK(CB, HK)                                                         \
  {                                                                           \
    f16x8 bf_[2][2];                                                          \
    _Pragma("unroll") for (int kc = 0; kc < 2; ++kc)                          \
      _Pragma("unroll") for (int nt = 0; nt < 2; ++nt)                        \
        bf_[kc][nt] = *(const f16x8*)&(CB)[boff[kc][nt]];                     \
    f16 hv_[4];                                                               \
    _Pragma("unroll") for (int t = 0; t < 4; ++t)                             \
      hv_[t] = hb[(HK) * 128 + t * 16];                                       \
    f16x8 sa0_[4], sa1_[4];                                                   \
    _Pragma("unroll") for (int t = 0; t < 4; ++t) {                           \
      sa0_[t] = xf[t][0] * hv_[t];                                            \
      sa1_[t] = xf[t][1] * hv_[t];                                            \
    }                                                                         \
    __builtin_amdgcn_s_setprio(1);                                            \
    _Pragma("unroll") for (int t = 0; t < 4; ++t)                             \
      _Pragma("unroll") for (int nt = 0; nt < 2; ++nt)                        \
        acc[t][nt] = __builtin_amdgcn_mfma_f32_16x16x32_f16(                  \
            sa0_[t], bf_[0][nt], acc[t][nt], 0, 0, 0);                        \
    _Pragma("unroll") for (int t = 0; t < 4; ++t)                             \
      _Pragma("unroll") for (int nt = 0; nt < 2; ++nt)                        \
        acc[t][nt] = __builtin_amdgcn_mfma_f32_16x16x32_f16(                  \
            sa1_[t], bf_[1][nt], acc[t][nt], 0, 0, 0);                        \
    __builtin_amdgcn_s_setprio(0);                                            \
  }

  // one group: wait (DMA issued last group, ~1700 cyc old) + barrier;
  // stage group G+1 into SD; compute chunks 2G, 2G+1 from slot SL.
#define GSTEP(G, SL, SD)                                                      \
  {                                                                           \
    asm volatile("s_waitcnt vmcnt(0) lgkmcnt(0)\n\ts_barrier" ::: "memory");  \
    __builtin_amdgcn_sched_barrier(0);                                        \
    {                                                                         \
      const f16* s_ = wsl + (size_t)((G) + 1) * 8192;                         \
      f16* d_ = &ring[(SD) * 8192 + wid * 2048];                              \
      _Pragma("unroll") for (int i_ = 0; i_ < 4; ++i_)                        \
        gload_lds16(s_ + i_ * 512, d_ + i_ * 512);                            \
    }                                                                         \
    __builtin_amdgcn_sched_barrier(0);                                        \
    const f16* gb_ = &ring[(SL) * 8192];                                      \
    CHUNK(gb_, 2 * (G));                                                      \
    CHUNK(gb_ + 4096, 2 * (G) + 1);                                           \
  }

  // ---- main loop: 64 groups (chunks 0..127); g=63 stages chunks 128,129
  #pragma unroll 1
  for (int g = 0; g < 64; g += 2) {
    GSTEP(g,     0, 1);
    GSTEP(g + 1, 1, 0);
  }
#undef GSTEP

  // ---- tail: chunk 128 (bias row, h == 1) from slot 0
  asm volatile("s_waitcnt vmcnt(0) lgkmcnt(0)\n\ts_barrier" ::: "memory");
  __builtin_amdgcn_sched_barrier(0);
  {
    f16x8 bf_[2][2];
    #pragma unroll
    for (int kc = 0; kc < 2; ++kc)
      #pragma unroll
      for (int nt = 0; nt < 2; ++nt)
        bf_[kc][nt] = *(const f16x8*)&ring[boff[kc][nt]];
    __builtin_amdgcn_s_setprio(1);
    #pragma unroll
    for (int t = 0; t < 4; ++t)
      #pragma unroll
      for (int nt = 0; nt < 2; ++nt) {
        acc[t][nt] = __builtin_amdgcn_mfma_f32_16x16x32_f16(
            xf[t][0], bf_[0][nt], acc[t][nt], 0, 0, 0);
        acc[t][nt] = __builtin_amdgcn_mfma_f32_16x16x32_f16(
            xf[t][1], bf_[1][nt], acc[t][nt], 0, 0, 0);
      }
    __builtin_amdgcn_s_setprio(0);
  }
#undef CHUNK

  // ---- epilogue: C row = quad*4 + reg, col = l15; scatter-add (full sums)
  #pragma unroll
  for (int t = 0; t < 4; ++t) {
    int ebase = e0 + mbase + t * 16 + quad * 4;
    int rc[4];
    #pragma unroll
    for (int r = 0; r < 4; ++r) rc[r] = receivers[ebase + r];
    #pragma unroll
    for (int nt = 0; nt < 2; ++nt) {
      int v = (nhalf * 2 + nt) * 16 + l15;
      #pragma unroll
      for (int r = 0; r < 4; ++r)
        atomicAdd(out + (size_t)rc[r] * WIDTH + v, acc[t][nt][r]);
    }
  }
}

extern "C" void kernel_launch(void* const* d_in, const int* in_sizes, int n_in,
                              void* d_out, int out_size, void* d_ws, size_t ws_size,
                              hipStream_t stream) {
  const float* x  = (const float*)d_in[0];
  const float* ea = (const float*)d_in[1];
  const float* W1 = (const float*)d_in[2];
  const float* b1 = (const float*)d_in[3];
  const float* W2 = (const float*)d_in[4];
  const float* b2 = (const float*)d_in[5];
  const int* snd  = (const int*)d_in[6];
  const int* rcv  = (const int*)d_in[7];
  float* out = (float*)d_out;
  f16* wsh = (f16*)d_ws;

  const int prep_grid = PADCH + XCONV_BLKS + ZBLKS;
  prep_kernel<<<prep_grid, 256, 0, stream>>>(x, W2, b2, wsh, out);
  nnconv_kernel<<<NUM_EDGES / BM, 256, 0, stream>>>(ea, W1, b1, snd, rcv, wsh, out);
}